// Round 1
// baseline (100.130 us; speedup 1.0000x reference)
//
#include <hip/hip_runtime.h>

// AGMBrain: N=128, B=32, IN_FEAT=4608, grid_size=3, num_candidates=8, n_steps=2
//
// Algebraic reduction (verified rounds 1-5):
//   einsum 'bdij,bdn->bdi' factorizes: messages[b,d,i] =
//     (sum_j T[b,d,i,j]) * (sum_n s[b,d,n])
//   Step 1 closed form: m1[b,d,i] = (colsum[d] + 128 t) * (At[d,i] + t*e[i]),
//     t = x_t[b,d], At[d,i] = sum_n EJ[i,n] NS[n,d], EJ[i,n] = sum_j ev[i,j,n],
//     e[i] = sum_n EJ[i,n]
//   Step 2 only needs i = 127: out[b,d] = relu((d!=127) * sig * (EJ[127,:]·s1))
//
// Round 7 (this round):
//  - x_t GEMM: 2bx2d tiles (1024 waves, 75 MB L2 read) -> 4bx4d tiles with
//    split-K halves per wave pair (512 waves = 128 blocks, 37.7 MB L2 read).
//    k1 grid = 256 blocks = 1/CU.  L2-bound 2.2us -> ~1.1us floor.
//  - k3 main loop was LDS-issue-bound: 5 ds_read_b32 per d per lane (640
//    LDS instrs vs 512 FMA). Re-pad rwlds 136->132 and obdT 33->36 so both
//    streams read as ds_read_b128: 5 LDS instrs per 4 d (160 total). obdT
//    staging writes become 8-way conflicted (stride 36 == 4 mod 32) but
//    that's only 16 instrs/thread vs ~4x saving in the 128-iter main loop.
// Harness floor note: ~85 us/iter is reset (268 MB 0xAA ws fill ~41 us +
// input restores); controllable share ~12.5 us entering this round.

#define KQ 1152  // 4608/4

__device__ __forceinline__ float wave_reduce64(float v) {
#pragma unroll
  for (int m = 32; m >= 1; m >>= 1) v += __shfl_xor(v, m);
  return v;
}
__device__ __forceinline__ float wave_reduce32(float v) {
#pragma unroll
  for (int m = 16; m >= 1; m >>= 1) v += __shfl_xor(v, m);
  return v;
}

// ws float offsets
#define WS_VT 0        // 16384: VT[d*128 + i] = At[d,i]
#define WS_E 16384     // 128:   e[i]
#define WS_EJ127 16512 // 128:   EJ[127, :]
#define WS_CS 16640    // 128:   colsum[d]
#define WS_XT 16768    // 4096:  x_t[b*128 + d]
#define WS_OBD 20864   // 4096:  out[b*128 + d]
// total 24960 floats = 100 KB

// K1: blocks 0..127  -> EJ row i (reduce over j), then At GEMV row:
//                       VT[d*128+i] = sum_n EJ[i,n] NS[n,d]; e[i]; EJ127;
//                       block 0 also emits colsum[d] = sum_n NS[n,d]
//     blocks 128..255 -> x_t, 2 tiles of 4b x 4d per block, K halved across
//                       wave pairs (waves 0,1 -> tile0; waves 2,3 -> tile1)
__global__ __launch_bounds__(256) void k1_pre(const float* __restrict__ ev,
                                              const float* __restrict__ ns,
                                              const float* __restrict__ x,
                                              const float* __restrict__ ipw,
                                              const float* __restrict__ ipb,
                                              float* __restrict__ ws) {
  int tid = threadIdx.x, blk = blockIdx.x;
  if (blk < 128) {
    __shared__ __align__(16) float4 sarr[256];
    __shared__ __align__(16) float ej[128];
    __shared__ float at2[2][128];
    __shared__ float cs2[2][128];
    int i = blk;
    int n4 = tid & 31, jg = tid >> 5;  // 8 j-groups x 16 j each
    const float4* ev4 = (const float4*)ev;
    float4 acc = make_float4(0.f, 0.f, 0.f, 0.f);
#pragma unroll
    for (int jj = 0; jj < 16; ++jj) {
      int j = jg * 16 + jj;
      float4 v = ev4[i * 4096 + j * 32 + n4];
      acc.x += v.x; acc.y += v.y; acc.z += v.z; acc.w += v.w;
    }
    sarr[tid] = acc;
    __syncthreads();
    if (tid < 32) {
      float4 s = sarr[tid];
#pragma unroll
      for (int k = 1; k < 8; ++k) {
        float4 v = sarr[tid + 32 * k];
        s.x += v.x; s.y += v.y; s.z += v.z; s.w += v.w;
      }
      int n0 = tid * 4;
      *(float4*)&ej[n0] = s;                           // EJ row -> LDS
      if (i == 127) *(float4*)(ws + WS_EJ127 + n0) = s;
      float p = s.x + s.y + s.z + s.w;
      p = wave_reduce32(p);
      if (tid == 0) (ws + WS_E)[i] = p;
    }
    __syncthreads();
    // At GEMV: d = tid&127, n-range split over h
    int d = tid & 127, h = tid >> 7;
    {
      const float* nsp = ns + h * 64 * 128 + d;   // coalesced across d
      const float* ejp = &ej[h * 64];             // broadcast reads
      float a = 0.f;
#pragma unroll 8
      for (int n = 0; n < 64; ++n) a += ejp[n] * nsp[n * 128];
      at2[h][d] = a;
    }
    if (i == 0) {  // colsum only in block 0
      const float* nsp = ns + h * 64 * 128 + d;
      float c = 0.f;
#pragma unroll 8
      for (int n = 0; n < 64; ++n) c += nsp[n * 128];
      cs2[h][d] = c;
    }
    __syncthreads();
    if (tid < 128) {
      (ws + WS_VT)[tid * 128 + i] = at2[0][tid] + at2[1][tid];  // scatter column
      if (i == 0) (ws + WS_CS)[tid] = cs2[0][tid] + cs2[1][tid];
    }
  } else {
    // x_t: tile 4b x 4d, K split in halves across wave pairs.
    __shared__ float sacc[4][16];
    int wv = tid >> 6, lane = tid & 63;
    int tile = (blk - 128) * 2 + (wv >> 1);  // 0..255
    int h = wv & 1;                          // K-half
    int b0 = (tile >> 5) << 2;               // 8 b-tiles
    int d0 = (tile & 31) << 2;               // 32 d-tiles
    const float4* x4 = (const float4*)x;
    const float4* w4 = (const float4*)ipw;
    float a[16];
#pragma unroll
    for (int k = 0; k < 16; ++k) a[k] = 0.f;
    int kq0 = h * 576 + lane;
    int kqe = h * 576 + 576;
#pragma unroll 3
    for (int kq = kq0; kq < kqe; kq += 64) {  // 9 iters
      float4 xr0 = x4[(b0 + 0) * KQ + kq];
      float4 xr1 = x4[(b0 + 1) * KQ + kq];
      float4 xr2 = x4[(b0 + 2) * KQ + kq];
      float4 xr3 = x4[(b0 + 3) * KQ + kq];
      float4 wc0 = w4[(d0 + 0) * KQ + kq];
      float4 wc1 = w4[(d0 + 1) * KQ + kq];
      float4 wc2 = w4[(d0 + 2) * KQ + kq];
      float4 wc3 = w4[(d0 + 3) * KQ + kq];
#define DOT4(X, W) ((X).x * (W).x + (X).y * (W).y + (X).z * (W).z + (X).w * (W).w)
      a[0]  += DOT4(xr0, wc0); a[1]  += DOT4(xr0, wc1);
      a[2]  += DOT4(xr0, wc2); a[3]  += DOT4(xr0, wc3);
      a[4]  += DOT4(xr1, wc0); a[5]  += DOT4(xr1, wc1);
      a[6]  += DOT4(xr1, wc2); a[7]  += DOT4(xr1, wc3);
      a[8]  += DOT4(xr2, wc0); a[9]  += DOT4(xr2, wc1);
      a[10] += DOT4(xr2, wc2); a[11] += DOT4(xr2, wc3);
      a[12] += DOT4(xr3, wc0); a[13] += DOT4(xr3, wc1);
      a[14] += DOT4(xr3, wc2); a[15] += DOT4(xr3, wc3);
#undef DOT4
    }
#pragma unroll
    for (int k = 0; k < 16; ++k) a[k] = wave_reduce64(a[k]);
    if (lane == 0) {
#pragma unroll
      for (int k = 0; k < 16; ++k) sacc[wv][k] = a[k];
    }
    __syncthreads();
    if (tid < 32) {
      int t2 = tid >> 4;          // which tile of this block
      int idx = tid & 15, r = idx >> 2, c = idx & 3;
      int tile2 = (blk - 128) * 2 + t2;
      int bb = ((tile2 >> 5) << 2) + r;
      int dd = ((tile2 & 31) << 2) + c;
      float v = sacc[t2 * 2][idx] + sacc[t2 * 2 + 1][idx];
      (ws + WS_XT)[bb * 128 + dd] = v + ipb[dd];
    }
  }
}

// K2: one tiny block per d: coalesced VT column + e + ej127 + colsum scalar,
// then register-resident step1+step2 for all 32 b.
__global__ __launch_bounds__(256) void k2_brain(float* __restrict__ ws) {
  __shared__ float xts[32];
  int tid = threadIdx.x, d = blockIdx.x;
  if (tid < 32) xts[tid] = (ws + WS_XT)[tid * 128 + d];
  __syncthreads();
  int wv = tid >> 6, l = tid & 63;
  float a0 = (ws + WS_VT)[d * 128 + l], a1 = (ws + WS_VT)[d * 128 + 64 + l];
  float e0 = (ws + WS_E)[l], e1 = (ws + WS_E)[l + 64];
  float q0 = (ws + WS_EJ127)[l], q1 = (ws + WS_EJ127)[l + 64];
  float csum = (ws + WS_CS)[d];
  bool z0 = (l == d), z1 = (l + 64 == d);
  float* obd = ws + WS_OBD;
#pragma unroll
  for (int bb = 0; bb < 8; ++bb) {
    int b = wv * 8 + bb;
    float t = xts[b];
    float s0s = csum + 128.f * t;
    float v0 = s0s * (a0 + t * e0);
    float v1 = s0s * (a1 + t * e1);
    v0 = z0 ? 0.f : fmaxf(v0, 0.f);  // step-1 mask + relu
    v1 = z1 ? 0.f : fmaxf(v1, 0.f);
    float sig = wave_reduce64(v0 + v1);
    float y = wave_reduce64(q0 * v0 + q1 * v1);
    if (l == 0) {
      float m2 = sig * y;
      if (d == 127) m2 = 0.f;  // step-2 mask (i=127)
      obd[b * 128 + d] = fmaxf(m2, 0.f);
    }
  }
}

// K3: blocks 0..143: recreation tile 32 f x 32 b; block 144: scores
// Main loop vectorized to ds_read_b128 on both LDS streams:
//   rwlds pad 132 (132f+4dq aligned; staging banks 33f%32=f conflict-free)
//   obdT pad 36   ((4dq+r)*36+4bg aligned; read slots 4dq+4bg conflict-free)
__global__ __launch_bounds__(256) void k3_proj(const float* __restrict__ rw,
                                               const float* __restrict__ rb,
                                               const float* __restrict__ sw,
                                               const float* __restrict__ sb,
                                               const float* __restrict__ ws,
                                               float* __restrict__ out) {
  const float* obd = ws + WS_OBD;
  int tid = threadIdx.x;
  int blk = blockIdx.x;
  if (blk < 144) {
    __shared__ __align__(16) float rwlds[32 * 132];
    __shared__ __align__(16) float obdT[128 * 36];
    int f0 = blk * 32;
    const float4* rw4 = (const float4*)rw;
#pragma unroll
    for (int it = 0; it < 4; ++it) {
      int q = tid + 256 * it;
      int f = q >> 5, n4 = q & 31;
      *(float4*)&rwlds[f * 132 + n4 * 4] = rw4[f0 * 32 + q];
    }
#pragma unroll
    for (int it = 0; it < 16; ++it) {
      int q = tid + 256 * it;
      int b = q >> 7, dd = q & 127;
      obdT[dd * 36 + b] = obd[q];  // 8-way write conflict, but only 16 instrs
    }
    __syncthreads();
    int f = tid >> 3, bg = tid & 7;
    float acc[4] = {0.f, 0.f, 0.f, 0.f};
#pragma unroll 8
    for (int dq = 0; dq < 32; ++dq) {
      float4 w  = *(const float4*)&rwlds[f * 132 + dq * 4];
      float4 p0 = *(const float4*)&obdT[(dq * 4 + 0) * 36 + bg * 4];
      float4 p1 = *(const float4*)&obdT[(dq * 4 + 1) * 36 + bg * 4];
      float4 p2 = *(const float4*)&obdT[(dq * 4 + 2) * 36 + bg * 4];
      float4 p3 = *(const float4*)&obdT[(dq * 4 + 3) * 36 + bg * 4];
      acc[0] += w.x * p0.x + w.y * p1.x + w.z * p2.x + w.w * p3.x;
      acc[1] += w.x * p0.y + w.y * p1.y + w.z * p2.y + w.w * p3.y;
      acc[2] += w.x * p0.z + w.y * p1.z + w.z * p2.z + w.w * p3.z;
      acc[3] += w.x * p0.w + w.y * p1.w + w.z * p2.w + w.w * p3.w;
    }
    float bias = rb[f0 + f];
#pragma unroll
    for (int k = 0; k < 4; ++k) out[(bg * 4 + k) * 4608 + f0 + f] = acc[k] + bias;
  } else {
    int b = tid >> 3, l8 = tid & 7;
    float acc = 0.f;
    for (int d = l8; d < 128; d += 8) acc += obd[b * 128 + d] * sw[d];
    acc += __shfl_xor(acc, 1);
    acc += __shfl_xor(acc, 2);
    acc += __shfl_xor(acc, 4);
    if (l8 == 0) out[147456 + b] = acc + sb[0];
  }
}

extern "C" void kernel_launch(void* const* d_in, const int* in_sizes, int n_in,
                              void* d_out, int out_size, void* d_ws, size_t ws_size,
                              hipStream_t stream) {
  const float* x   = (const float*)d_in[0];   // (32, 4608)
  const float* ipw = (const float*)d_in[1];   // (128, 4608)
  const float* ipb = (const float*)d_in[2];   // (128,)
  const float* ns  = (const float*)d_in[3];   // (128, 128)
  const float* ev  = (const float*)d_in[4];   // (128, 128, 128)
  const float* rw  = (const float*)d_in[5];   // (4608, 128)
  const float* rb  = (const float*)d_in[6];   // (4608,)
  const float* sw  = (const float*)d_in[7];   // (1, 128)
  const float* sb  = (const float*)d_in[8];   // (1,)
  float* out = (float*)d_out;                 // 147456 recreation + 32 scores
  float* ws = (float*)d_ws;                   // uses 24960 floats (~100 KB)

  k1_pre<<<256, 256, 0, stream>>>(ev, ns, x, ipw, ipb, ws);
  k2_brain<<<128, 256, 0, stream>>>(ws);
  k3_proj<<<145, 256, 0, stream>>>(rw, rb, sw, sb, ws, out);
}